// Round 1
// baseline (852.367 us; speedup 1.0000x reference)
//
#include <hip/hip_runtime.h>
#include <stdint.h>

typedef unsigned short u16;
typedef short v8s __attribute__((ext_vector_type(8)));
typedef float v4f __attribute__((ext_vector_type(4)));

#define DIM 192
#define NH 6
#define WZ 8
#define NTOK 64
#define IMG 224
#define NWIN 28
#define NB 8
#define SHF 4
#define NWINDOWS (NB*NWIN*NWIN)
#define SCALE 0.17677669529663687f

#define XA_STR 200    // 192 + 8 pad (bf16)  -> stride 100 words ≡ 4 mod 32
#define QKV_STR 584   // 576 + 8 pad (bf16)  -> 292 words ≡ 4 mod 32
#define P_STR 72      // 64 + 8 pad  (bf16)  -> 36 words  ≡ 4 mod 32
#define STG_STR 193   // 192 + 1 pad (fp32)  -> ≡ 1 mod 32

__device__ __forceinline__ u16 f2bf(float f) {
    union { float f; uint32_t u; } v; v.f = f;
    return (u16)((v.u + 0x7FFFu + ((v.u >> 16) & 1u)) >> 16);
}

// ---- prep: bf16-convert weights, expand rel-pos bias table ----
__global__ void prep_kernel(const float* __restrict__ qkv_w,
                            const float* __restrict__ proj_w,
                            const float* __restrict__ rel_bias,
                            const int* __restrict__ rel_idx,
                            u16* __restrict__ qw, u16* __restrict__ pw,
                            float* __restrict__ bias_tab) {
    int i = blockIdx.x * 256 + threadIdx.x;
    if (i < 3*DIM*DIM) qw[i] = f2bf(qkv_w[i]);
    if (i < DIM*DIM)   pw[i] = f2bf(proj_w[i]);
    if (i < NH*NTOK*NTOK) {
        int h  = i / (NTOK*NTOK);
        int ij = i - h*(NTOK*NTOK);
        bias_tab[i] = rel_bias[rel_idx[ij]*NH + h];   // [h][i][j]
    }
}

// ---- fused window attention: one block per window, one wave per head ----
__global__ __launch_bounds__(384) void winattn_kernel(
    const float* __restrict__ x,
    const float* __restrict__ qkv_b,
    const float* __restrict__ proj_b,
    const u16* __restrict__ qw,
    const u16* __restrict__ pw,
    const float* __restrict__ bias_tab,
    float* __restrict__ out)
{
    __shared__ __align__(16) u16 xa[NTOK * XA_STR];      // 25600 B: x window (bf16), later attn_out
    __shared__ __align__(16) u16 qkvs[NTOK * QKV_STR];   // 74752 B: qkv (bf16)
    __shared__ __align__(16) u16 scr[NH * NTOK * P_STR]; // 55296 B: P per head; reused as f32 staging

    const int tid = threadIdx.x;
    const int wv  = tid >> 6;          // wave = head
    const int l15 = tid & 15;
    const int lhi = (tid & 63) >> 4;   // 0..3

    const int b  = blockIdx.x / (NWIN*NWIN);
    const int rm = blockIdx.x % (NWIN*NWIN);
    const int wi = rm / NWIN;
    const int wj = rm % NWIN;

    // ---------- phase 0: gather (roll -4 folded into index) ----------
    const float* xb = x + (size_t)b * DIM*IMG*IMG;
    #pragma unroll
    for (int it = 0; it < 32; ++it) {
        int flat = it*384 + tid;
        int c = flat >> 6;
        int t = flat & 63;
        int hh = wi*WZ + (t >> 3) + SHF; if (hh >= IMG) hh -= IMG;
        int ww = wj*WZ + (t & 7)  + SHF; if (ww >= IMG) ww -= IMG;
        xa[t*XA_STR + c] = f2bf(xb[(size_t)c*(IMG*IMG) + hh*IMG + ww]);
    }
    __syncthreads();

    // ---------- phase 1: QKV GEMM, wave wv owns output cols [wv*96, wv*96+96) ----------
    {
        v4f acc[4][6];
        #pragma unroll
        for (int mt = 0; mt < 4; ++mt)
            #pragma unroll
            for (int nt = 0; nt < 6; ++nt)
                acc[mt][nt] = (v4f){0.f,0.f,0.f,0.f};

        #pragma unroll
        for (int kk = 0; kk < 6; ++kk) {
            v8s afr[4];
            #pragma unroll
            for (int mt = 0; mt < 4; ++mt)
                afr[mt] = *(const v8s*)&xa[(mt*16 + l15)*XA_STR + kk*32 + lhi*8];
            #pragma unroll
            for (int nt = 0; nt < 6; ++nt) {
                int o = wv*96 + nt*16 + l15;
                v8s bfr = *(const v8s*)(qw + o*DIM + kk*32 + lhi*8);
                #pragma unroll
                for (int mt = 0; mt < 4; ++mt)
                    acc[mt][nt] = __builtin_amdgcn_mfma_f32_16x16x32_bf16(afr[mt], bfr, acc[mt][nt], 0, 0, 0);
            }
        }
        // + bias, fold SCALE into q, write bf16 to LDS
        #pragma unroll
        for (int nt = 0; nt < 6; ++nt) {
            int o = wv*96 + nt*16 + l15;
            float bb = qkv_b[o];
            float sc = (o < DIM) ? SCALE : 1.0f;
            #pragma unroll
            for (int mt = 0; mt < 4; ++mt)
                #pragma unroll
                for (int r = 0; r < 4; ++r)
                    qkvs[(mt*16 + lhi*4 + r)*QKV_STR + o] = f2bf((acc[mt][nt][r] + bb) * sc);
        }
    }
    __syncthreads();

    // ---------- phase 2: attention for head h = wv ----------
    const int h = wv;
    v4f oacc[4][2];
    {
        v8s qfr[4], kfr[4];
        #pragma unroll
        for (int mt = 0; mt < 4; ++mt)
            qfr[mt] = *(const v8s*)&qkvs[(mt*16 + l15)*QKV_STR + h*32 + lhi*8];
        #pragma unroll
        for (int nt = 0; nt < 4; ++nt)
            kfr[nt] = *(const v8s*)&qkvs[(nt*16 + l15)*QKV_STR + DIM + h*32 + lhi*8];

        v4f sacc[4][4];
        #pragma unroll
        for (int mt = 0; mt < 4; ++mt)
            #pragma unroll
            for (int ct = 0; ct < 4; ++ct)
                sacc[mt][ct] = (v4f){0.f,0.f,0.f,0.f};
        #pragma unroll
        for (int mt = 0; mt < 4; ++mt)
            #pragma unroll
            for (int ct = 0; ct < 4; ++ct)
                sacc[mt][ct] = __builtin_amdgcn_mfma_f32_16x16x32_bf16(qfr[mt], kfr[ct], sacc[mt][ct], 0, 0, 0);

        // + rel-pos bias (fp32, L2-resident table)
        const float* bt = bias_tab + h*NTOK*NTOK;
        #pragma unroll
        for (int mt = 0; mt < 4; ++mt)
            #pragma unroll
            for (int ct = 0; ct < 4; ++ct)
                #pragma unroll
                for (int r = 0; r < 4; ++r)
                    sacc[mt][ct][r] += bt[(mt*16 + lhi*4 + r)*NTOK + ct*16 + l15];

        // fp32 softmax per row: 4 regs (ct) + 16-lane shfl_xor reduce
        #pragma unroll
        for (int mt = 0; mt < 4; ++mt) {
            #pragma unroll
            for (int r = 0; r < 4; ++r) {
                float mx = fmaxf(fmaxf(sacc[mt][0][r], sacc[mt][1][r]),
                                 fmaxf(sacc[mt][2][r], sacc[mt][3][r]));
                #pragma unroll
                for (int d = 8; d >= 1; d >>= 1) mx = fmaxf(mx, __shfl_xor(mx, d, 64));
                float s = 0.f;
                #pragma unroll
                for (int ct = 0; ct < 4; ++ct) {
                    float e = __expf(sacc[mt][ct][r] - mx);
                    sacc[mt][ct][r] = e; s += e;
                }
                #pragma unroll
                for (int d = 8; d >= 1; d >>= 1) s += __shfl_xor(s, d, 64);
                float inv = 1.f / s;
                #pragma unroll
                for (int ct = 0; ct < 4; ++ct) sacc[mt][ct][r] *= inv;
            }
        }

        // P -> bf16 -> per-head LDS scratch (C-layout -> A-frag layout round-trip)
        u16* Ph = scr + h*NTOK*P_STR;
        #pragma unroll
        for (int mt = 0; mt < 4; ++mt)
            #pragma unroll
            for (int ct = 0; ct < 4; ++ct)
                #pragma unroll
                for (int r = 0; r < 4; ++r)
                    Ph[(mt*16 + lhi*4 + r)*P_STR + ct*16 + l15] = f2bf(sacc[mt][ct][r]);

        // PV: O = P @ V
        #pragma unroll
        for (int mt = 0; mt < 4; ++mt)
            #pragma unroll
            for (int nt = 0; nt < 2; ++nt)
                oacc[mt][nt] = (v4f){0.f,0.f,0.f,0.f};
        #pragma unroll
        for (int kk = 0; kk < 2; ++kk) {
            v8s pfr[4];
            #pragma unroll
            for (int mt = 0; mt < 4; ++mt)
                pfr[mt] = *(const v8s*)&Ph[(mt*16 + l15)*P_STR + kk*32 + lhi*8];
            #pragma unroll
            for (int nt = 0; nt < 2; ++nt) {
                v8s vfr;
                u16* ve = (u16*)&vfr;
                #pragma unroll
                for (int j = 0; j < 8; ++j)   // V B-frag: column read (scalar for now)
                    ve[j] = qkvs[(kk*32 + lhi*8 + j)*QKV_STR + 2*DIM + h*32 + nt*16 + l15];
                #pragma unroll
                for (int mt = 0; mt < 4; ++mt)
                    oacc[mt][nt] = __builtin_amdgcn_mfma_f32_16x16x32_bf16(pfr[mt], vfr, oacc[mt][nt], 0, 0, 0);
            }
        }
    }

    // attn_out -> xa (bf16), head cols [h*32, h*32+32)
    #pragma unroll
    for (int mt = 0; mt < 4; ++mt)
        #pragma unroll
        for (int nt = 0; nt < 2; ++nt)
            #pragma unroll
            for (int r = 0; r < 4; ++r)
                xa[(mt*16 + lhi*4 + r)*XA_STR + h*32 + nt*16 + l15] = f2bf(oacc[mt][nt][r]);
    __syncthreads();   // all waves: attn_out complete AND P reads complete

    // ---------- phase 3: proj GEMM, wave wv owns cols [wv*32, wv*32+32) ----------
    float* stg = (float*)scr;
    {
        v4f pacc[4][2];
        #pragma unroll
        for (int mt = 0; mt < 4; ++mt)
            #pragma unroll
            for (int nt = 0; nt < 2; ++nt)
                pacc[mt][nt] = (v4f){0.f,0.f,0.f,0.f};
        #pragma unroll
        for (int kk = 0; kk < 6; ++kk) {
            v8s afr[4];
            #pragma unroll
            for (int mt = 0; mt < 4; ++mt)
                afr[mt] = *(const v8s*)&xa[(mt*16 + l15)*XA_STR + kk*32 + lhi*8];
            #pragma unroll
            for (int nt = 0; nt < 2; ++nt) {
                int o = wv*32 + nt*16 + l15;
                v8s bfr = *(const v8s*)(pw + o*DIM + kk*32 + lhi*8);
                #pragma unroll
                for (int mt = 0; mt < 4; ++mt)
                    pacc[mt][nt] = __builtin_amdgcn_mfma_f32_16x16x32_bf16(afr[mt], bfr, pacc[mt][nt], 0, 0, 0);
            }
        }
        // + proj bias, fp32 staging for coalesced scatter
        #pragma unroll
        for (int nt = 0; nt < 2; ++nt) {
            int o = wv*32 + nt*16 + l15;
            float bb = proj_b[o];
            #pragma unroll
            for (int mt = 0; mt < 4; ++mt)
                #pragma unroll
                for (int r = 0; r < 4; ++r)
                    stg[(mt*16 + lhi*4 + r)*STG_STR + o] = pacc[mt][nt][r] + bb;
        }
    }
    __syncthreads();

    // ---------- phase 4: scatter (roll +4 == same pixels as gather) ----------
    const float* cstg = (const float*)scr;
    float* ob = out + (size_t)b * DIM*IMG*IMG;
    #pragma unroll
    for (int it = 0; it < 32; ++it) {
        int flat = it*384 + tid;
        int c = flat >> 6;
        int t = flat & 63;
        int hh = wi*WZ + (t >> 3) + SHF; if (hh >= IMG) hh -= IMG;
        int ww = wj*WZ + (t & 7)  + SHF; if (ww >= IMG) ww -= IMG;
        ob[(size_t)c*(IMG*IMG) + hh*IMG + ww] = cstg[t*STG_STR + c];
    }
}

extern "C" void kernel_launch(void* const* d_in, const int* in_sizes, int n_in,
                              void* d_out, int out_size, void* d_ws, size_t ws_size,
                              hipStream_t stream) {
    const float* x        = (const float*)d_in[0];
    const float* qkv_w    = (const float*)d_in[1];
    const float* qkv_b    = (const float*)d_in[2];
    const float* proj_w   = (const float*)d_in[3];
    const float* proj_b   = (const float*)d_in[4];
    const float* rel_bias = (const float*)d_in[5];
    const int*   rel_idx  = (const int*)d_in[6];

    u16*   qw_bf    = (u16*)d_ws;                            // 221184 B
    u16*   pw_bf    = (u16*)((char*)d_ws + 221184);          //  73728 B
    float* bias_tab = (float*)((char*)d_ws + 294912);        //  98304 B
    float* out      = (float*)d_out;

    hipLaunchKernelGGL(prep_kernel, dim3(432), dim3(256), 0, stream,
                       qkv_w, proj_w, rel_bias, rel_idx, qw_bf, pw_bf, bias_tab);
    hipLaunchKernelGGL(winattn_kernel, dim3(NWINDOWS), dim3(384), 0, stream,
                       x, qkv_b, proj_b, qw_bf, pw_bf, bias_tab, out);
}

// Round 3
// 777.449 us; speedup vs baseline: 1.0964x; 1.0964x over previous
//
#include <hip/hip_runtime.h>
#include <stdint.h>

typedef unsigned short u16;
typedef short v8s __attribute__((ext_vector_type(8)));
typedef float v4f __attribute__((ext_vector_type(4)));

#define DIM 192
#define NH 6
#define NTOK 64
#define IMG 224
#define NWIN 28
#define NB 8
#define NWINDOWS (NB*NWIN*NWIN)
#define SCALE 0.17677669529663687f

#define XA_STR 200   // bf16 stride, x-window / attn_out tile
#define HSTR 72      // bf16 stride, per-head Q|K / P / V^T region
#define STG_STR 194  // fp32 stride, scatter staging

__device__ __forceinline__ u16 f2bf(float f) {
    union { float f; uint32_t u; } v; v.f = f;
    return (u16)((v.u + 0x7FFFu + ((v.u >> 16) & 1u)) >> 16);
}

// ---- prep: bf16 weights (SCALE folded into q rows), scaled bias, expanded bias table ----
__global__ void prep_kernel(const float* __restrict__ qkv_w,
                            const float* __restrict__ qkv_b,
                            const float* __restrict__ proj_w,
                            const float* __restrict__ rel_bias,
                            const int* __restrict__ rel_idx,
                            u16* __restrict__ qw, u16* __restrict__ pw,
                            float* __restrict__ qb2, float* __restrict__ biasT) {
    int i = blockIdx.x * 256 + threadIdx.x;
    if (i < 3*DIM*DIM) {
        float s = (i < DIM*DIM) ? SCALE : 1.f;   // rows [0,192) are Wq
        qw[i] = f2bf(qkv_w[i] * s);
    }
    if (i < DIM*DIM) pw[i] = f2bf(proj_w[i]);
    if (i < 3*DIM)   qb2[i] = qkv_b[i] * (i < DIM ? SCALE : 1.f);
    if (i < NH*NTOK*NTOK) {
        int h   = i >> 12;          // biasT[h][query][key], key minor
        int qk2 = i & 4095;
        biasT[i] = rel_bias[rel_idx[qk2]*NH + h];
    }
}

// ---- fused window attention: one block per window, wave wv owns head wv ----
__global__ __launch_bounds__(384, 3) void winattn_kernel(
    const float* __restrict__ x,
    const float* __restrict__ proj_b,
    const u16* __restrict__ qw,
    const u16* __restrict__ pw,
    const float* __restrict__ qb2,
    const float* __restrict__ biasT,
    float* __restrict__ out)
{
    __shared__ __align__(16) u16 xa[NTOK * XA_STR];     // 25600 B: x window; later attn_out
    __shared__ __align__(16) u16 qkp[NH * NTOK * HSTR]; // 55296 B: per-head Q|K -> P -> V^T; later fp32 staging
    float* stgf = (float*)qkp;                           // 64*194*4 = 49664 <= 55296

    const int tid  = threadIdx.x;
    const int wv   = tid >> 6;          // wave = head
    const int lane = tid & 63;
    const int l15  = lane & 15;
    const int g    = lane >> 4;         // 0..3

    // XCD swizzle: dispatch i -> XCD i%8; each XCD gets one full image (784 windows)
    const int b  = blockIdx.x & 7;
    const int rm = blockIdx.x >> 3;     // 0..783
    const int wi = rm / NWIN;
    const int wj = rm % NWIN;

    // gather/scatter geometry: thread -> (4 tokens of one window row, channels c0+24*it)
    const int qq   = tid & 15;
    const int trow = qq >> 1;           // 0..7
    const int tcol = (qq & 1) * 4;      // 0 or 4
    const int t0   = trow*8 + tcol;
    const int c0   = tid >> 4;          // 0..23
    int hh = wi*8 + trow + 4; if (hh >= IMG) hh -= IMG;   // roll(-4) folded in
    int ww = wj*8 + tcol + 4; if (ww >= IMG) ww -= IMG;   // 16B vector never straddles wrap
    const size_t pixoff = (size_t)hh*IMG + ww;

    u16* Hh = qkp + wv*(NTOK*HSTR);     // this wave's head region (wave-private)

    // ---------- phase 0: gather (float4) ----------
    const float* xb = x + (size_t)b * DIM*IMG*IMG;
    {
        v4f buf[8];
        #pragma unroll
        for (int it = 0; it < 8; ++it)
            buf[it] = *(const v4f*)(xb + (size_t)(c0 + it*24)*(IMG*IMG) + pixoff);
        #pragma unroll
        for (int it = 0; it < 8; ++it) {
            int c = c0 + it*24;
            xa[(t0+0)*XA_STR + c] = f2bf(buf[it][0]);
            xa[(t0+1)*XA_STR + c] = f2bf(buf[it][1]);
            xa[(t0+2)*XA_STR + c] = f2bf(buf[it][2]);
            xa[(t0+3)*XA_STR + c] = f2bf(buf[it][3]);
        }
    }
    __syncthreads();

    // ---------- phase 1: QKV GEMM; wave wv computes q,k,v cols of head wv ----------
    uint32_t vd[4][2][2];   // packed V rows: vd[mt][ntl][p] = V[16mt+4g+2p+{0,1}][ntl*16+l15]
    {
        v4f acc[4][6];
        #pragma unroll
        for (int mt = 0; mt < 4; ++mt)
            #pragma unroll
            for (int nt = 0; nt < 6; ++nt)
                acc[mt][nt] = (v4f){0.f,0.f,0.f,0.f};

        #pragma unroll
        for (int kk = 0; kk < 6; ++kk) {
            v8s afr[4];
            #pragma unroll
            for (int mt = 0; mt < 4; ++mt)
                afr[mt] = *(const v8s*)&xa[(mt*16 + l15)*XA_STR + kk*32 + g*8];
            #pragma unroll
            for (int nt = 0; nt < 6; ++nt) {
                int o = (nt>>1)*DIM + wv*32 + (nt&1)*16 + l15;
                v8s bfr = *(const v8s*)(qw + (size_t)o*DIM + kk*32 + g*8);
                #pragma unroll
                for (int mt = 0; mt < 4; ++mt)
                    acc[mt][nt] = __builtin_amdgcn_mfma_f32_16x16x32_bf16(afr[mt], bfr, acc[mt][nt], 0, 0, 0);
            }
        }
        // epilogue: Q -> Hh cols [0,32), K -> Hh cols [32,64) (token-major); V -> packed regs
        #pragma unroll
        for (int ntl = 0; ntl < 2; ++ntl) {
            const int col = ntl*16 + l15;          // head-local feature
            const float bq = qb2[wv*32 + col];
            const float bk = qb2[DIM + wv*32 + col];
            const float bv = qb2[2*DIM + wv*32 + col];
            #pragma unroll
            for (int mt = 0; mt < 4; ++mt) {
                #pragma unroll
                for (int r = 0; r < 4; ++r) {
                    const int row = mt*16 + 4*g + r;
                    Hh[row*HSTR + col]      = f2bf(acc[mt][ntl][r]   + bq);
                    Hh[row*HSTR + 32 + col] = f2bf(acc[mt][2+ntl][r] + bk);
                }
                vd[mt][ntl][0] = (uint32_t)f2bf(acc[mt][4+ntl][0]+bv) |
                                 ((uint32_t)f2bf(acc[mt][4+ntl][1]+bv) << 16);
                vd[mt][ntl][1] = (uint32_t)f2bf(acc[mt][4+ntl][2]+bv) |
                                 ((uint32_t)f2bf(acc[mt][4+ntl][3]+bv) << 16);
            }
        }
    }
    __syncthreads();   // all xa reads done -> attn_out may overwrite xa later

    // ---------- phase 2: attention, head wv (entirely wave-private) ----------
    v4f oacc[4][2];    // [mt][ntl]: O[query = mt*16+4g+r][d = ntl*16+l15]
    {
        v8s qfr[4], kfr[4];
        #pragma unroll
        for (int t = 0; t < 4; ++t) {
            qfr[t] = *(const v8s*)&Hh[(t*16 + l15)*HSTR + g*8];
            kfr[t] = *(const v8s*)&Hh[(t*16 + l15)*HSTR + 32 + g*8];
        }
        // S = Q K^T : sacc[mt][ct][r] = S[query=mt*16+4g+r][key=ct*16+l15]
        v4f sacc[4][4];
        #pragma unroll
        for (int mt = 0; mt < 4; ++mt)
            #pragma unroll
            for (int ct = 0; ct < 4; ++ct)
                sacc[mt][ct] = __builtin_amdgcn_mfma_f32_16x16x32_bf16(qfr[mt], kfr[ct],
                                    (v4f){0.f,0.f,0.f,0.f}, 0, 0, 0);

        // + bias, softmax over keys (4 in-lane regs + 16-lane shfl_xor reduce)
        const float* bt = biasT + wv*(NTOK*NTOK);
        #pragma unroll
        for (int mt = 0; mt < 4; ++mt) {
            #pragma unroll
            for (int r = 0; r < 4; ++r) {
                const int qrow = mt*16 + 4*g + r;
                float v0 = sacc[mt][0][r] + bt[qrow*NTOK +  0 + l15];
                float v1 = sacc[mt][1][r] + bt[qrow*NTOK + 16 + l15];
                float v2 = sacc[mt][2][r] + bt[qrow*NTOK + 32 + l15];
                float v3 = sacc[mt][3][r] + bt[qrow*NTOK + 48 + l15];
                float mx = fmaxf(fmaxf(v0, v1), fmaxf(v2, v3));
                #pragma unroll
                for (int d = 8; d >= 1; d >>= 1) mx = fmaxf(mx, __shfl_xor(mx, d));
                v0 = __expf(v0 - mx); v1 = __expf(v1 - mx);
                v2 = __expf(v2 - mx); v3 = __expf(v3 - mx);
                float sum = v0 + v1 + v2 + v3;
                #pragma unroll
                for (int d = 8; d >= 1; d >>= 1) sum += __shfl_xor(sum, d);
                float inv = 1.f / sum;
                sacc[mt][0][r] = v0*inv; sacc[mt][1][r] = v1*inv;
                sacc[mt][2][r] = v2*inv; sacc[mt][3][r] = v3*inv;
            }
        }

        // P -> Hh (overwrites Q|K; qfr/kfr already in regs; wave-private ordering)
        #pragma unroll
        for (int mt = 0; mt < 4; ++mt)
            #pragma unroll
            for (int ct = 0; ct < 4; ++ct)
                #pragma unroll
                for (int r = 0; r < 4; ++r)
                    Hh[(mt*16 + 4*g + r)*HSTR + ct*16 + l15] = f2bf(sacc[mt][ct][r]);

        // P A-frags back (both K-halves, before V^T overlays rows 0..31)
        v8s pfr[2][4];
        #pragma unroll
        for (int kk = 0; kk < 2; ++kk)
            #pragma unroll
            for (int mt = 0; mt < 4; ++mt)
                pfr[kk][mt] = *(const v8s*)&Hh[(mt*16 + l15)*HSTR + kk*32 + g*8];

        // V^T -> Hh rows [0,32): VT[d][k], k minor (dword pair stores from vd)
        #pragma unroll
        for (int mt = 0; mt < 4; ++mt)
            #pragma unroll
            for (int ntl = 0; ntl < 2; ++ntl)
                #pragma unroll
                for (int p = 0; p < 2; ++p)
                    *(uint32_t*)&Hh[(ntl*16 + l15)*HSTR + mt*16 + 4*g + 2*p] = vd[mt][ntl][p];

        // V^T B-frags + PV MFMAs
        v8s vfr[2][2];
        #pragma unroll
        for (int kk = 0; kk < 2; ++kk)
            #pragma unroll
            for (int ntl = 0; ntl < 2; ++ntl)
                vfr[kk][ntl] = *(const v8s*)&Hh[(ntl*16 + l15)*HSTR + kk*32 + g*8];

        #pragma unroll
        for (int mt = 0; mt < 4; ++mt)
            #pragma unroll
            for (int ntl = 0; ntl < 2; ++ntl)
                oacc[mt][ntl] = (v4f){0.f,0.f,0.f,0.f};
        #pragma unroll
        for (int kk = 0; kk < 2; ++kk)
            #pragma unroll
            for (int mt = 0; mt < 4; ++mt)
                #pragma unroll
                for (int ntl = 0; ntl < 2; ++ntl)
                    oacc[mt][ntl] = __builtin_amdgcn_mfma_f32_16x16x32_bf16(pfr[kk][mt], vfr[kk][ntl], oacc[mt][ntl], 0, 0, 0);
    }
    // attn_out -> xa cols [wv*32, wv*32+32)
    #pragma unroll
    for (int mt = 0; mt < 4; ++mt)
        #pragma unroll
        for (int ntl = 0; ntl < 2; ++ntl)
            #pragma unroll
            for (int r = 0; r < 4; ++r)
                xa[(mt*16 + 4*g + r)*XA_STR + wv*32 + ntl*16 + l15] = f2bf(oacc[mt][ntl][r]);
    __syncthreads();   // attn_out complete; all qkp reads done -> staging may overwrite qkp

    // ---------- phase 3: proj GEMM, wave wv owns cols [wv*32, wv*32+32) ----------
    {
        v4f pacc[4][2];
        #pragma unroll
        for (int mt = 0; mt < 4; ++mt)
            #pragma unroll
            for (int ntl = 0; ntl < 2; ++ntl)
                pacc[mt][ntl] = (v4f){0.f,0.f,0.f,0.f};
        #pragma unroll
        for (int kk = 0; kk < 6; ++kk) {
            v8s afr[4];
            #pragma unroll
            for (int mt = 0; mt < 4; ++mt)
                afr[mt] = *(const v8s*)&xa[(mt*16 + l15)*XA_STR + kk*32 + g*8];
            #pragma unroll
            for (int ntl = 0; ntl < 2; ++ntl) {
                int o = wv*32 + ntl*16 + l15;
                v8s bfr = *(const v8s*)(pw + (size_t)o*DIM + kk*32 + g*8);
                #pragma unroll
                for (int mt = 0; mt < 4; ++mt)
                    pacc[mt][ntl] = __builtin_amdgcn_mfma_f32_16x16x32_bf16(afr[mt], bfr, pacc[mt][ntl], 0, 0, 0);
            }
        }
        #pragma unroll
        for (int ntl = 0; ntl < 2; ++ntl) {
            int o = wv*32 + ntl*16 + l15;
            float bb = proj_b[o];
            #pragma unroll
            for (int mt = 0; mt < 4; ++mt)
                #pragma unroll
                for (int r = 0; r < 4; ++r)
                    stgf[(mt*16 + 4*g + r)*STG_STR + o] = pacc[mt][ntl][r] + bb;
        }
    }
    __syncthreads();

    // ---------- phase 4: scatter (float4, same pixels as gather) ----------
    float* ob = out + (size_t)b * DIM*IMG*IMG;
    #pragma unroll
    for (int it = 0; it < 8; ++it) {
        int c = c0 + it*24;
        v4f vv = { stgf[(t0+0)*STG_STR + c], stgf[(t0+1)*STG_STR + c],
                   stgf[(t0+2)*STG_STR + c], stgf[(t0+3)*STG_STR + c] };
        *(v4f*)(ob + (size_t)c*(IMG*IMG) + pixoff) = vv;
    }
}

extern "C" void kernel_launch(void* const* d_in, const int* in_sizes, int n_in,
                              void* d_out, int out_size, void* d_ws, size_t ws_size,
                              hipStream_t stream) {
    const float* x        = (const float*)d_in[0];
    const float* qkv_w    = (const float*)d_in[1];
    const float* qkv_b    = (const float*)d_in[2];
    const float* proj_w   = (const float*)d_in[3];
    const float* proj_b   = (const float*)d_in[4];
    const float* rel_bias = (const float*)d_in[5];
    const int*   rel_idx  = (const int*)d_in[6];

    u16*   qw_bf  = (u16*)d_ws;                         // 221184 B
    u16*   pw_bf  = (u16*)((char*)d_ws + 221184);       //  73728 B
    float* qb2    = (float*)((char*)d_ws + 294912);     //   2304 B
    float* biasT  = (float*)((char*)d_ws + 297216);     //  98304 B
    float* out    = (float*)d_out;

    hipLaunchKernelGGL(prep_kernel, dim3(432), dim3(256), 0, stream,
                       qkv_w, qkv_b, proj_w, rel_bias, rel_idx, qw_bf, pw_bf, qb2, biasT);
    hipLaunchKernelGGL(winattn_kernel, dim3(NWINDOWS), dim3(384), 0, stream,
                       x, proj_b, qw_bf, pw_bf, qb2, biasT, out);
}

// Round 5
// 682.766 us; speedup vs baseline: 1.2484x; 1.1387x over previous
//
#include <hip/hip_runtime.h>
#include <stdint.h>

typedef unsigned short u16;
typedef short v8s __attribute__((ext_vector_type(8)));
typedef float v4f __attribute__((ext_vector_type(4)));
typedef uint32_t v2u __attribute__((ext_vector_type(2)));

#define DIM 192
#define NH 6
#define NTOK 64
#define IMG 224
#define NWIN 28
#define NB 8
#define NWINDOWS (NB*NWIN*NWIN)
#define SCALE 0.17677669529663687f

#define X_STR 200    // bf16 stride for X window tile   (dword stride ≡4 mod 32: 2-way free)
#define AO_STR 200   // bf16 stride for attn_out tile

__device__ __forceinline__ u16 f2bf(float f) {
    union { float f; uint32_t u; } v; v.f = f;
    return (u16)((v.u + 0x7FFFu + ((v.u >> 16) & 1u)) >> 16);
}
// pack 2 f32 -> 2 bf16 in one dword (lo = first arg) — proven f2bf path, no asm
__device__ __forceinline__ uint32_t pk2(float lo, float hi) {
    return (uint32_t)f2bf(lo) | ((uint32_t)f2bf(hi) << 16);
}

// ---- prep: bf16 weights (SCALE folded into q rows), scaled bias, expanded bias table ----
__global__ void prep_kernel(const float* __restrict__ qkv_w,
                            const float* __restrict__ qkv_b,
                            const float* __restrict__ proj_w,
                            const float* __restrict__ rel_bias,
                            const int* __restrict__ rel_idx,
                            u16* __restrict__ qw, u16* __restrict__ pw,
                            float* __restrict__ qb2, float* __restrict__ biasT) {
    int i = blockIdx.x * 256 + threadIdx.x;
    if (i < 3*DIM*DIM) {
        float s = (i < DIM*DIM) ? SCALE : 1.f;   // rows [0,192) are Wq
        qw[i] = f2bf(qkv_w[i] * s);
    }
    if (i < DIM*DIM) pw[i] = f2bf(proj_w[i]);
    if (i < 3*DIM)   qb2[i] = qkv_b[i] * (i < DIM ? SCALE : 1.f);
    if (i < NH*NTOK*NTOK) {
        int h   = i >> 12;          // biasT[h][query][key], key minor
        int qk2 = i & 4095;
        biasT[i] = rel_bias[rel_idx[qk2]*NH + h];
    }
}

// ---- fused window attention: one block per window, wave wv owns head wv ----
__global__ __launch_bounds__(384, 3) void winattn_kernel(
    const float* __restrict__ x,
    const float* __restrict__ proj_b,
    const u16* __restrict__ qw,
    const u16* __restrict__ pw,
    const float* __restrict__ qb2,
    const float* __restrict__ biasT,
    float* __restrict__ out)
{
    // bufA: X [64][200] (ph0-1) -> heads 0-2 Q|K swizzled [64][64] (ph1-2) -> AO [64][200] (ph2-3)
    // bufB: heads 3-5 Q|K swizzled [64][64]
    __shared__ __align__(16) u16 bufA[NTOK * X_STR];   // 25600 B
    __shared__ __align__(16) u16 bufB[3 * NTOK * 64];  // 24576 B   (total 50176 B)

    const int tid  = threadIdx.x;
    const int wv   = tid >> 6;          // wave = head
    const int lane = tid & 63;
    const int l15  = lane & 15;
    const int g    = lane >> 4;         // 0..3

    // XCD swizzle: dispatch i -> XCD i%8; each XCD gets one full image (784 windows)
    const int b  = blockIdx.x & 7;
    const int rm = blockIdx.x >> 3;     // 0..783
    const int wi = rm / NWIN;
    const int wj = rm % NWIN;

    // gather geometry: thread -> (4 tokens of one window row, channels c0+24*it)
    const int qq   = tid & 15;
    const int trow = qq >> 1;           // 0..7
    const int tcol = (qq & 1) * 4;      // 0 or 4
    const int t0   = trow*8 + tcol;
    const int c0   = tid >> 4;          // 0..23
    int ghh = wi*8 + trow + 4; if (ghh >= IMG) ghh -= IMG;   // roll(-4) folded in
    int gww = wj*8 + tcol + 4; if (gww >= IMG) gww -= IMG;   // 16B vector never straddles wrap
    const size_t pixoff = (size_t)ghh*IMG + gww;

    u16* Hh = (wv < 3) ? (bufA + wv*(NTOK*64)) : (bufB + (wv-3)*(NTOK*64));

    // ---------- phase 0: gather (float4) ----------
    const float* xb = x + (size_t)b * DIM*IMG*IMG;
    {
        v4f buf[8];
        #pragma unroll
        for (int it = 0; it < 8; ++it)
            buf[it] = *(const v4f*)(xb + (size_t)(c0 + it*24)*(IMG*IMG) + pixoff);
        #pragma unroll
        for (int it = 0; it < 8; ++it) {
            int c = c0 + it*24;
            bufA[(t0+0)*X_STR + c] = f2bf(buf[it][0]);
            bufA[(t0+1)*X_STR + c] = f2bf(buf[it][1]);
            bufA[(t0+2)*X_STR + c] = f2bf(buf[it][2]);
            bufA[(t0+3)*X_STR + c] = f2bf(buf[it][3]);
        }
    }
    __syncthreads();   // B1

    // ---------- phase 1: QKV GEMM; wave wv computes q,k,v of head wv ----------
    v4f acc[4][6];
    #pragma unroll
    for (int mt = 0; mt < 4; ++mt)
        #pragma unroll
        for (int nt = 0; nt < 6; ++nt)
            acc[mt][nt] = (v4f){0.f,0.f,0.f,0.f};

    #pragma unroll
    for (int kk = 0; kk < 6; ++kk) {
        v8s afr[4];
        #pragma unroll
        for (int mt = 0; mt < 4; ++mt)
            afr[mt] = *(const v8s*)&bufA[(mt*16 + l15)*X_STR + kk*32 + g*8];
        #pragma unroll
        for (int nt = 0; nt < 6; ++nt) {
            int o = (nt>>1)*DIM + wv*32 + (nt&1)*16 + l15;
            v8s bfr = *(const v8s*)(qw + (size_t)o*DIM + kk*32 + g*8);
            #pragma unroll
            for (int mt = 0; mt < 4; ++mt)
                acc[mt][nt] = __builtin_amdgcn_mfma_f32_16x16x32_bf16(afr[mt], bfr, acc[mt][nt], 0, 0, 0);
        }
    }
    __syncthreads();   // B2: all X reads done -> Q|K may overwrite bufA

    // epilogue: Q,K -> swizzled head tile (feat ^ (tok&7)<<3); V -> packed regs
    uint32_t vd[4][2][2];   // vd[mt][ntl][p] = V[16mt+4g+2p+{0,1}][ntl*16+l15]
    #pragma unroll
    for (int ntl = 0; ntl < 2; ++ntl) {
        const int col = ntl*16 + l15;          // head-local feature 0..31
        const float bq = qb2[wv*32 + col];
        const float bk = qb2[DIM + wv*32 + col];
        const float bv = qb2[2*DIM + wv*32 + col];
        #pragma unroll
        for (int mt = 0; mt < 4; ++mt) {
            #pragma unroll
            for (int r = 0; r < 4; ++r) {
                const int tok = mt*16 + 4*g + r;
                const int sw  = (tok & 7) << 3;
                Hh[tok*64 + (col ^ sw)]        = f2bf(acc[mt][ntl][r]   + bq);
                Hh[tok*64 + ((32 + col) ^ sw)] = f2bf(acc[mt][2+ntl][r] + bk);
            }
            vd[mt][ntl][0] = pk2(acc[mt][4+ntl][0]+bv, acc[mt][4+ntl][1]+bv);
            vd[mt][ntl][1] = pk2(acc[mt][4+ntl][2]+bv, acc[mt][4+ntl][3]+bv);
        }
    }

    // frag reads (own head only — same-wave LDS ordering, no barrier needed)
    v8s qfr[4], kfr[4];
    #pragma unroll
    for (int t = 0; t < 4; ++t) {
        const int tok = t*16 + l15;
        const int sw  = (tok & 7) << 3;
        qfr[t] = *(const v8s*)&Hh[tok*64 + ((g*8) ^ sw)];
        kfr[t] = *(const v8s*)&Hh[tok*64 + ((32 + g*8) ^ sw)];
    }
    __syncthreads();   // B3: all frag reads done -> AO may overwrite bufA

    // ---------- phase 2: attention (no LDS at all) ----------
    // S^T = K Q^T : sacc[kt][qt][r] = S[key=16kt+4g+r][query=16qt+l15]
    v4f sacc[4][4];
    #pragma unroll
    for (int kt = 0; kt < 4; ++kt)
        #pragma unroll
        for (int qt = 0; qt < 4; ++qt)
            sacc[kt][qt] = __builtin_amdgcn_mfma_f32_16x16x32_bf16(kfr[kt], qfr[qt],
                                (v4f){0.f,0.f,0.f,0.f}, 0, 0, 0);

    // + bias (float4), softmax over keys: 16 in-lane + shfl_xor(16,32)
    const float* bt = biasT + wv*(NTOK*NTOK);
    #pragma unroll
    for (int qt = 0; qt < 4; ++qt) {
        #pragma unroll
        for (int kt = 0; kt < 4; ++kt) {
            v4f bb = *(const v4f*)&bt[(qt*16 + l15)*NTOK + kt*16 + 4*g];
            sacc[kt][qt] += bb;
        }
        float mx = sacc[0][qt][0];
        #pragma unroll
        for (int kt = 0; kt < 4; ++kt)
            #pragma unroll
            for (int r = 0; r < 4; ++r) mx = fmaxf(mx, sacc[kt][qt][r]);
        mx = fmaxf(mx, __shfl_xor(mx, 16));
        mx = fmaxf(mx, __shfl_xor(mx, 32));
        float sum = 0.f;
        #pragma unroll
        for (int kt = 0; kt < 4; ++kt)
            #pragma unroll
            for (int r = 0; r < 4; ++r) {
                float e = __expf(sacc[kt][qt][r] - mx);
                sacc[kt][qt][r] = e; sum += e;
            }
        sum += __shfl_xor(sum, 16);
        sum += __shfl_xor(sum, 32);
        float inv = 1.f / sum;
        #pragma unroll
        for (int kt = 0; kt < 4; ++kt)
            #pragma unroll
            for (int r = 0; r < 4; ++r) sacc[kt][qt][r] *= inv;
    }

    // O^T = V^T P^T via pure register repacks. Slot convention on BOTH operands:
    // slot (g,j) of kk-th MFMA holds key 16*(2kk+(j>>2)) + 4g + (j&3).
    v4f oT[2][4];   // [ntl][qt]: O[query=16qt+l15][d=16ntl+4g+r]
    #pragma unroll
    for (int ntl = 0; ntl < 2; ++ntl)
        #pragma unroll
        for (int qt = 0; qt < 4; ++qt)
            oT[ntl][qt] = (v4f){0.f,0.f,0.f,0.f};
    #pragma unroll
    for (int kk = 0; kk < 2; ++kk) {
        v8s vfr[2];
        #pragma unroll
        for (int ntl = 0; ntl < 2; ++ntl) {
            union { v8s v; uint32_t d[4]; } u;
            u.d[0] = vd[2*kk  ][ntl][0]; u.d[1] = vd[2*kk  ][ntl][1];
            u.d[2] = vd[2*kk+1][ntl][0]; u.d[3] = vd[2*kk+1][ntl][1];
            vfr[ntl] = u.v;
        }
        #pragma unroll
        for (int qt = 0; qt < 4; ++qt) {
            union { v8s v; uint32_t d[4]; } p;
            p.d[0] = pk2(sacc[2*kk  ][qt][0], sacc[2*kk  ][qt][1]);
            p.d[1] = pk2(sacc[2*kk  ][qt][2], sacc[2*kk  ][qt][3]);
            p.d[2] = pk2(sacc[2*kk+1][qt][0], sacc[2*kk+1][qt][1]);
            p.d[3] = pk2(sacc[2*kk+1][qt][2], sacc[2*kk+1][qt][3]);
            #pragma unroll
            for (int ntl = 0; ntl < 2; ++ntl)
                oT[ntl][qt] = __builtin_amdgcn_mfma_f32_16x16x32_bf16(vfr[ntl], p.v, oT[ntl][qt], 0, 0, 0);
        }
    }

    // attn_out -> bufA [64][AO_STR], b64 stores (4 consecutive feats per lane)
    #pragma unroll
    for (int qt = 0; qt < 4; ++qt)
        #pragma unroll
        for (int ntl = 0; ntl < 2; ++ntl) {
            v2u o;
            o.x = pk2(oT[ntl][qt][0], oT[ntl][qt][1]);
            o.y = pk2(oT[ntl][qt][2], oT[ntl][qt][3]);
            *(v2u*)&bufA[(qt*16 + l15)*AO_STR + wv*32 + ntl*16 + 4*g] = o;
        }
    __syncthreads();   // B4: AO complete

    // ---------- phase 3: transposed proj GEMM + direct register scatter ----------
    v4f pacc[2][4];    // [ntl][qt]: P[out=wv*32+16ntl+4g+r][tok=16qt+l15]
    #pragma unroll
    for (int ntl = 0; ntl < 2; ++ntl)
        #pragma unroll
        for (int qt = 0; qt < 4; ++qt)
            pacc[ntl][qt] = (v4f){0.f,0.f,0.f,0.f};
    #pragma unroll
    for (int kk = 0; kk < 6; ++kk) {
        v8s aofr[4];
        #pragma unroll
        for (int qt = 0; qt < 4; ++qt)
            aofr[qt] = *(const v8s*)&bufA[(qt*16 + l15)*AO_STR + kk*32 + g*8];
        #pragma unroll
        for (int ntl = 0; ntl < 2; ++ntl) {
            v8s pwfr = *(const v8s*)(pw + (size_t)(wv*32 + ntl*16 + l15)*DIM + kk*32 + g*8);
            #pragma unroll
            for (int qt = 0; qt < 4; ++qt)
                pacc[ntl][qt] = __builtin_amdgcn_mfma_f32_16x16x32_bf16(pwfr, aofr[qt], pacc[ntl][qt], 0, 0, 0);
        }
    }
    // bias + scatter straight from registers (32B row segments, roll(+4) == gather pixels)
    float pb[2][4];
    #pragma unroll
    for (int ntl = 0; ntl < 2; ++ntl)
        #pragma unroll
        for (int r = 0; r < 4; ++r)
            pb[ntl][r] = proj_b[wv*32 + ntl*16 + 4*g + r];

    float* ob = out + (size_t)b * DIM*IMG*IMG;
    #pragma unroll
    for (int qt = 0; qt < 4; ++qt) {
        const int strow = 2*qt + (l15 >> 3);
        const int stcol = l15 & 7;
        int hh = wi*8 + strow + 4; if (hh >= IMG) hh -= IMG;
        int ww = wj*8 + stcol + 4; if (ww >= IMG) ww -= IMG;
        const size_t pix = (size_t)hh*IMG + ww;
        #pragma unroll
        for (int ntl = 0; ntl < 2; ++ntl)
            #pragma unroll
            for (int r = 0; r < 4; ++r) {
                const int c = wv*32 + ntl*16 + 4*g + r;
                ob[(size_t)c*(IMG*IMG) + pix] = pacc[ntl][qt][r] + pb[ntl][r];
            }
    }
}

extern "C" void kernel_launch(void* const* d_in, const int* in_sizes, int n_in,
                              void* d_out, int out_size, void* d_ws, size_t ws_size,
                              hipStream_t stream) {
    const float* x        = (const float*)d_in[0];
    const float* qkv_w    = (const float*)d_in[1];
    const float* qkv_b    = (const float*)d_in[2];
    const float* proj_w   = (const float*)d_in[3];
    const float* proj_b   = (const float*)d_in[4];
    const float* rel_bias = (const float*)d_in[5];
    const int*   rel_idx  = (const int*)d_in[6];

    u16*   qw_bf  = (u16*)d_ws;                         // 221184 B
    u16*   pw_bf  = (u16*)((char*)d_ws + 221184);       //  73728 B
    float* qb2    = (float*)((char*)d_ws + 294912);     //   2304 B
    float* biasT  = (float*)((char*)d_ws + 297216);     //  98304 B
    float* out    = (float*)d_out;

    hipLaunchKernelGGL(prep_kernel, dim3(432), dim3(256), 0, stream,
                       qkv_w, qkv_b, proj_w, rel_bias, rel_idx, qw_bf, pw_bf, qb2, biasT);
    hipLaunchKernelGGL(winattn_kernel, dim3(NWINDOWS), dim3(384), 0, stream,
                       x, proj_b, qw_bf, pw_bf, qb2, biasT, out);
}